// Round 6
// baseline (1249.482 us; speedup 1.0000x reference)
//
#include <hip/hip_runtime.h>
#include <hip/hip_bf16.h>
#include <hip/hip_cooperative_groups.h>
#include <cstdint>
#include <cstddef>

// ODE: dy/dt = tanh(y@W1+b1)@W2+b2.
// RK4: 7 steps h=0.2 + 1 step h=0.15 -> 32 flow evals; interior outputs via
// cubic Hermite dense output (f from adjacent steps' k1; final step uses k4).
// Preferred path: ONE persistent cooperative kernel, 512 blocks x 128 thr,
// 32 KB LDS (2-ring dbuf -> >=2 blocks/CU under any occupancy accounting),
// phases separated by grid.sync(). Occupancy-gated + error-checked fallback
// to an equivalent multi-kernel sequence (R4-class perf) if coop can't launch.

namespace cg = cooperative_groups;

#define GAS __attribute__((address_space(1)))
#define LAS __attribute__((address_space(3)))

typedef __bf16 bf16x8 __attribute__((ext_vector_type(8)));
typedef float  f32x4  __attribute__((ext_vector_type(4)));
typedef unsigned short u16;

struct Ptrs {
  const float *x, *W1, *b1, *W2, *b2;
  float* out;
  u16 *W1t, *W2t, *ybf, *ytbf, *Abuf;
  float *y, *part, *k1a, *k1b, *kb2, *kb3, *kb4;
};

__device__ __forceinline__ u16 f2bf(float f) {
  __hip_bfloat16 h = __float2bfloat16(f);
  return __builtin_bit_cast(u16, h);
}

__device__ __forceinline__ int swz(int id) {  // XCD swizzle for 512 blocks
  return (id & 7) * 64 + (id >> 3);
}

// ---------------- transpose: W[K][N] fp32 -> Wt[N][K] bf16 (128 thr) ----------------
__device__ __forceinline__ void transpose_dev(
    const float* __restrict__ W, u16* __restrict__ Wt, int K, int N,
    int wg, int tid, u16* scratch /* >= 32*33 u16 */) {
  const int ntk = K >> 5, ntn = N >> 5;
  const int ntiles = ntk * ntn;
  const int tx = tid & 31, ty = tid >> 5;  // 32 x 4
  for (int t = wg; t < ntiles; t += 512) {
    int kb = (t % ntk) << 5, nb = (t / ntk) << 5;
    __syncthreads();
    #pragma unroll
    for (int i = 0; i < 32; i += 4)
      scratch[(ty + i) * 33 + tx] = f2bf(W[(size_t)(kb + ty + i) * N + nb + tx]);
    __syncthreads();
    #pragma unroll
    for (int i = 0; i < 32; i += 4)
      Wt[(size_t)(nb + ty + i) * K + kb + tx] = scratch[tx * 33 + ty + i];
  }
}

// ---------------- setup: transposes + y=ybf=out0=x ----------------
__device__ __forceinline__ void do_setup(const Ptrs& p, int wg, int tid,
                                         u16* scratch) {
  transpose_dev(p.W1, p.W1t, 1024, 4096, wg, tid, scratch);
  transpose_dev(p.W2, p.W2t, 4096, 1024, wg, tid, scratch);
  const float4* x4 = (const float4*)p.x;
  #pragma unroll
  for (int r = 0; r < 2; ++r) {
    int i = wg * 256 + r * 128 + tid;
    float4 v = x4[i];
    ((float4*)p.y)[i] = v;
    ((float4*)p.out)[i] = v;
    ((ushort4*)p.ybf)[i] =
        make_ushort4(f2bf(v.x), f2bf(v.y), f2bf(v.z), f2bf(v.w));
  }
}

// ---------------- staging: one 64x64 bf16 tile pair via global_load_lds ----------------
// LDS rows 128B; XOR swizzle slot ^= (row&7) on the GLOBAL source (LDS dest
// linear per gload_lds rules), matching the swizzled ds_read.
__device__ __forceinline__ void stage_tiles(
    const u16* __restrict__ A, const u16* __restrict__ Bt,
    char* AsB, char* BsB, int m0, int n0, int kt, int K, int tid) {
  #pragma unroll
  for (int i = 0; i < 4; ++i) {
    int j = i * 128 + tid;
    int row = j >> 3, slot = j & 7;
    int kc = slot ^ (row & 7);
    __builtin_amdgcn_global_load_lds(
        (const GAS void*)(A + (size_t)(m0 + row) * K + kt + kc * 8),
        (LAS void*)(AsB + j * 16), 16, 0, 0);
  }
  #pragma unroll
  for (int i = 0; i < 4; ++i) {
    int j = i * 128 + tid;
    int row = j >> 3, slot = j & 7;
    int kc = slot ^ (row & 7);
    __builtin_amdgcn_global_load_lds(
        (const GAS void*)(Bt + (size_t)(n0 + row) * K + kt + kc * 8),
        (LAS void*)(BsB + j * 16), 16, 0, 0);
  }
}

// ---------------- GEMM core: C = A[M][K] @ Bt[N][K]^T ----------------
// BM=BN=BK=64, 2 waves (row halves), wave tile 32x64, mfma 16x16x32.
// 2-ring LDS double buffer (32 KB), stage-next || compute-cur, 1 barrier/iter.
template<int TANH>
__device__ void gemm_core(
    const u16* __restrict__ A, const u16* __restrict__ Bt,
    const float* __restrict__ bias, u16* __restrict__ Cbf,
    float* __restrict__ Cf, int K, int Nn,
    int m0, int n0, int k0, int Kc,
    u16 (*As)[4096], u16 (*Bs)[4096], int tid) {
  const int lane = tid & 63;
  const int wid  = tid >> 6;
  const int lrow = lane & 15;
  const int kgrp = lane >> 4;
  const int nt = Kc >> 6;  // 16

  f32x4 acc[2][4];
  #pragma unroll
  for (int m = 0; m < 2; ++m)
    #pragma unroll
    for (int n = 0; n < 4; ++n) acc[m][n] = (f32x4){0.f, 0.f, 0.f, 0.f};

  stage_tiles(A, Bt, (char*)As[0], (char*)Bs[0], m0, n0, k0, K, tid);
  __syncthreads();

  int cur = 0;
  for (int t = 0; t < nt; ++t) {
    if (t + 1 < nt)
      stage_tiles(A, Bt, (char*)As[cur ^ 1], (char*)Bs[cur ^ 1],
                  m0, n0, k0 + (t + 1) * 64, K, tid);
    const char* AsB = (const char*)As[cur];
    const char* BsB = (const char*)Bs[cur];
    #pragma unroll
    for (int ks = 0; ks < 2; ++ks) {
      bf16x8 af[2], bfr[4];
      #pragma unroll
      for (int m = 0; m < 2; ++m) {
        int row = wid * 32 + m * 16 + lrow;
        int slot = (ks * 4 + kgrp) ^ (row & 7);
        af[m] = *(const bf16x8*)(AsB + row * 128 + slot * 16);
      }
      #pragma unroll
      for (int n = 0; n < 4; ++n) {
        int row = n * 16 + lrow;
        int slot = (ks * 4 + kgrp) ^ (row & 7);
        bfr[n] = *(const bf16x8*)(BsB + row * 128 + slot * 16);
      }
      #pragma unroll
      for (int m = 0; m < 2; ++m)
        #pragma unroll
        for (int n = 0; n < 4; ++n)
          acc[m][n] = __builtin_amdgcn_mfma_f32_16x16x32_bf16(
              af[m], bfr[n], acc[m][n], 0, 0, 0);
    }
    __syncthreads();
    cur ^= 1;
  }

  // epilogue — C/D layout: col = lane&15, row = (lane>>4)*4 + reg (m89)
  #pragma unroll
  for (int m = 0; m < 2; ++m) {
    #pragma unroll
    for (int n = 0; n < 4; ++n) {
      int gcol = n0 + n * 16 + lrow;
      #pragma unroll
      for (int r = 0; r < 4; ++r) {
        int grow = m0 + wid * 32 + m * 16 + kgrp * 4 + r;
        float v = acc[m][n][r];
        if (TANH) {
          v = tanhf(v + bias[gcol]);
          Cbf[(size_t)grow * Nn + gcol] = f2bf(v);
        } else {
          Cf[(size_t)grow * Nn + gcol] = v;
        }
      }
    }
  }
}

__device__ __forceinline__ void do_gemm1(const Ptrs& p, int wg, int tid, int e,
                                         u16 (*As)[4096], u16 (*Bs)[4096]) {
  const u16* yin = (e == 1) ? p.ybf : p.ytbf;
  gemm_core<1>(yin, p.W1t, p.b1, p.Abuf, nullptr, 1024, 4096,
               (wg & 7) * 64, (wg >> 3) * 64, 0, 1024, As, Bs, tid);
}

__device__ __forceinline__ void do_gemm2(const Ptrs& p, int wg, int tid,
                                         u16 (*As)[4096], u16 (*Bs)[4096]) {
  const int bz = wg >> 7;  // split-K=4
  gemm_core<0>(p.Abuf, p.W2t, nullptr, nullptr,
               p.part + (size_t)bz * 524288, 4096, 1024,
               (wg & 7) * 64, ((wg >> 3) & 15) * 64, bz * 1024, 1024,
               As, Bs, tid);
}

// ---------------- combine + RK4 algebra + fused Hermite ----------------
__device__ __forceinline__ void do_combine(const Ptrs& p, int wg, int tid,
                                           int n, int e) {
  const int q = 131072;  // MN/4 float4s
  const float h = (n < 7) ? 0.2f : 0.15f;
  const float h6 = h / 6.f;
  const float coef = (e == 3) ? h : h * 0.5f;
  float* k1buf = (n & 1) ? p.k1b : p.k1a;
  const float* k1prev = (n & 1) ? p.k1a : p.k1b;
  // Hermite coefs (theta=1/4,1/2,3/4 at h=0.2): {y0, f0*h, y1, f1*h}
  const float4 hc0 = {0.84375f, 0.028125f, 0.15625f, -0.009375f};
  const float4 hc1 = {0.5f,     0.025f,    0.5f,     -0.025f};
  const float4 hc2 = {0.15625f, 0.009375f, 0.84375f, -0.028125f};
  const float4* p4  = (const float4*)p.part;
  const float4* b24 = (const float4*)p.b2;
  const float4* yv4 = (const float4*)p.y;

  #pragma unroll
  for (int r = 0; r < 2; ++r) {
    int i = wg * 256 + r * 128 + tid;
    float4 s0 = p4[i], s1 = p4[q + i], s2 = p4[2 * q + i], s3 = p4[3 * q + i];
    float4 bb = b24[i & 255];
    float4 F;
    F.x = s0.x + s1.x + s2.x + s3.x + bb.x;
    F.y = s0.y + s1.y + s2.y + s3.y + bb.y;
    F.z = s0.z + s1.z + s2.z + s3.z + bb.z;
    F.w = s0.w + s1.w + s2.w + s3.w + bb.w;
    float4 yv = yv4[i];
    float4 nv;
    if (e < 4) {
      float* kbuf = (e == 1) ? k1buf : (e == 2 ? p.kb2 : p.kb3);
      ((float4*)kbuf)[i] = F;
      nv.x = yv.x + coef * F.x;
      nv.y = yv.y + coef * F.y;
      nv.z = yv.z + coef * F.z;
      nv.w = yv.w + coef * F.w;
      ((ushort4*)p.ytbf)[i] =
          make_ushort4(f2bf(nv.x), f2bf(nv.y), f2bf(nv.z), f2bf(nv.w));
      // fused Hermite for interval n-1 (f1 = F = k1 of step n)
      if (e == 1 && n >= 1) {
        const float4* y04 = (const float4*)p.out + (size_t)(4 * (n - 1)) * q;
        const float4* y14 = (const float4*)p.out + (size_t)(4 * n) * q;
        float4 A_ = y04[i], B_ = y14[i], C_ = ((const float4*)k1prev)[i];
        float4* o4 = (float4*)p.out;
        float4 o;
        o.x = hc0.x * A_.x + hc0.y * C_.x + hc0.z * B_.x + hc0.w * F.x;
        o.y = hc0.x * A_.y + hc0.y * C_.y + hc0.z * B_.y + hc0.w * F.y;
        o.z = hc0.x * A_.z + hc0.y * C_.z + hc0.z * B_.z + hc0.w * F.z;
        o.w = hc0.x * A_.w + hc0.y * C_.w + hc0.z * B_.w + hc0.w * F.w;
        o4[(size_t)(4 * (n - 1) + 1) * q + i] = o;
        o.x = hc1.x * A_.x + hc1.y * C_.x + hc1.z * B_.x + hc1.w * F.x;
        o.y = hc1.x * A_.y + hc1.y * C_.y + hc1.z * B_.y + hc1.w * F.y;
        o.z = hc1.x * A_.z + hc1.y * C_.z + hc1.z * B_.z + hc1.w * F.z;
        o.w = hc1.x * A_.w + hc1.y * C_.w + hc1.z * B_.w + hc1.w * F.w;
        o4[(size_t)(4 * (n - 1) + 2) * q + i] = o;
        o.x = hc2.x * A_.x + hc2.y * C_.x + hc2.z * B_.x + hc2.w * F.x;
        o.y = hc2.x * A_.y + hc2.y * C_.y + hc2.z * B_.y + hc2.w * F.y;
        o.z = hc2.x * A_.z + hc2.y * C_.z + hc2.z * B_.z + hc2.w * F.z;
        o.w = hc2.x * A_.w + hc2.y * C_.w + hc2.z * B_.w + hc2.w * F.w;
        o4[(size_t)(4 * (n - 1) + 3) * q + i] = o;
      }
    } else {
      if (n == 7) ((float4*)p.kb4)[i] = F;
      float4 a = ((const float4*)k1buf)[i];
      float4 c = ((const float4*)p.kb2)[i];
      float4 d = ((const float4*)p.kb3)[i];
      nv.x = yv.x + h6 * (a.x + 2.f * c.x + 2.f * d.x + F.x);
      nv.y = yv.y + h6 * (a.y + 2.f * c.y + 2.f * d.y + F.y);
      nv.z = yv.z + h6 * (a.z + 2.f * c.z + 2.f * d.z + F.z);
      nv.w = yv.w + h6 * (a.w + 2.f * c.w + 2.f * d.w + F.w);
      ((float4*)p.y)[i] = nv;
      int outIdx = (n < 7) ? 4 * (n + 1) : 31;
      ((float4*)p.out)[(size_t)outIdx * q + i] = nv;
      ((ushort4*)p.ybf)[i] =
          make_ushort4(f2bf(nv.x), f2bf(nv.y), f2bf(nv.z), f2bf(nv.w));
    }
  }
}

// tail Hermite: interval [out28, out31], h=0.15, theta=1/3, 2/3
__device__ __forceinline__ void do_tail(const Ptrs& p, int wg, int tid) {
  const int q = 131072;
  const float4 tc0 = {0.7407407f, 0.0222222f, 0.2592593f, -0.0111111f};
  const float4 tc1 = {0.2592593f, 0.0111111f, 0.7407407f, -0.0222222f};
  float4* o4 = (float4*)p.out;
  #pragma unroll
  for (int r = 0; r < 2; ++r) {
    int i = wg * 256 + r * 128 + tid;
    float4 A_ = o4[(size_t)28 * q + i];
    float4 B_ = o4[(size_t)31 * q + i];
    float4 C_ = ((const float4*)p.k1b)[i];  // k1 of step 7 (7&1 -> k1b)
    float4 D_ = ((const float4*)p.kb4)[i];
    float4 o;
    o.x = tc0.x * A_.x + tc0.y * C_.x + tc0.z * B_.x + tc0.w * D_.x;
    o.y = tc0.x * A_.y + tc0.y * C_.y + tc0.z * B_.y + tc0.w * D_.y;
    o.z = tc0.x * A_.z + tc0.y * C_.z + tc0.z * B_.z + tc0.w * D_.z;
    o.w = tc0.x * A_.w + tc0.y * C_.w + tc0.z * B_.w + tc0.w * D_.w;
    o4[(size_t)29 * q + i] = o;
    o.x = tc1.x * A_.x + tc1.y * C_.x + tc1.z * B_.x + tc1.w * D_.x;
    o.y = tc1.x * A_.y + tc1.y * C_.y + tc1.z * B_.y + tc1.w * D_.y;
    o.z = tc1.x * A_.z + tc1.y * C_.z + tc1.z * B_.z + tc1.w * D_.z;
    o.w = tc1.x * A_.w + tc1.y * C_.w + tc1.z * B_.w + tc1.w * D_.w;
    o4[(size_t)30 * q + i] = o;
  }
}

// ---------------- persistent cooperative kernel ----------------
__global__ __launch_bounds__(128, 1) void ode_persistent(Ptrs p) {
  __shared__ __attribute__((aligned(16))) u16 As[2][4096];
  __shared__ __attribute__((aligned(16))) u16 Bs[2][4096];
  cg::grid_group grid = cg::this_grid();
  const int tid = threadIdx.x;
  const int wg  = swz(blockIdx.x);

  do_setup(p, wg, tid, (u16*)As);
  grid.sync();

  for (int n = 0; n < 8; ++n) {
    for (int e = 1; e <= 4; ++e) {
      do_gemm1(p, wg, tid, e, As, Bs);
      grid.sync();
      do_gemm2(p, wg, tid, As, Bs);
      grid.sync();
      do_combine(p, wg, tid, n, e);
      grid.sync();
    }
  }
  do_tail(p, wg, tid);
}

// ---------------- fallback wrappers (multi-kernel path) ----------------
__global__ __launch_bounds__(128) void setup_k(Ptrs p) {
  __shared__ u16 scratch[32 * 33];
  do_setup(p, swz(blockIdx.x), threadIdx.x, scratch);
}
__global__ __launch_bounds__(128) void gemm1_k(Ptrs p, int e) {
  __shared__ __attribute__((aligned(16))) u16 As[2][4096];
  __shared__ __attribute__((aligned(16))) u16 Bs[2][4096];
  do_gemm1(p, swz(blockIdx.x), threadIdx.x, e, As, Bs);
}
__global__ __launch_bounds__(128) void gemm2_k(Ptrs p) {
  __shared__ __attribute__((aligned(16))) u16 As[2][4096];
  __shared__ __attribute__((aligned(16))) u16 Bs[2][4096];
  do_gemm2(p, swz(blockIdx.x), threadIdx.x, As, Bs);
}
__global__ __launch_bounds__(128) void combine_k(Ptrs p, int n, int e) {
  do_combine(p, swz(blockIdx.x), threadIdx.x, n, e);
}
__global__ __launch_bounds__(128) void tail_k(Ptrs p) {
  do_tail(p, swz(blockIdx.x), threadIdx.x);
}

extern "C" void kernel_launch(void* const* d_in, const int* in_sizes, int n_in,
                              void* d_out, int out_size, void* d_ws, size_t ws_size,
                              hipStream_t stream) {
  Ptrs p;
  p.x  = (const float*)d_in[0];
  p.W1 = (const float*)d_in[1];
  p.b1 = (const float*)d_in[2];
  p.W2 = (const float*)d_in[3];
  p.b2 = (const float*)d_in[4];
  p.out = (float*)d_out;

  const int Dq = 1024, Hq = 4096;
  const int MN = 512 * 1024;
  char* ws = (char*)d_ws;
  size_t off = 0;
  p.W1t  = (u16*)(ws + off);   off += (size_t)Hq * Dq * 2;
  p.W2t  = (u16*)(ws + off);   off += (size_t)Dq * Hq * 2;
  p.y    = (float*)(ws + off); off += (size_t)MN * 4;
  p.ybf  = (u16*)(ws + off);   off += (size_t)MN * 2;
  p.ytbf = (u16*)(ws + off);   off += (size_t)MN * 2;
  p.Abuf = (u16*)(ws + off);   off += (size_t)512 * Hq * 2;
  p.part = (float*)(ws + off); off += (size_t)4 * MN * 4;
  p.k1a  = (float*)(ws + off); off += (size_t)MN * 4;
  p.k1b  = (float*)(ws + off); off += (size_t)MN * 4;
  p.kb2  = (float*)(ws + off); off += (size_t)MN * 4;
  p.kb3  = (float*)(ws + off); off += (size_t)MN * 4;
  p.kb4  = (float*)(ws + off); off += (size_t)MN * 4;
  if (ws_size < off) return;

  // occupancy gate (host-side queries only -> graph-capture safe)
  int dev = 0;
  (void)hipGetDevice(&dev);
  int numCU = 0;
  (void)hipDeviceGetAttribute(&numCU, hipDeviceAttributeMultiprocessorCount, dev);
  int maxb = 0;
  (void)hipOccupancyMaxActiveBlocksPerMultiprocessor(&maxb, ode_persistent, 128, 0);

  hipError_t st = hipErrorUnknown;
  if (maxb > 0 && (long)maxb * numCU >= 512) {
    void* args[] = {&p};
    st = hipLaunchCooperativeKernel((void*)ode_persistent, dim3(512),
                                    dim3(128), args, 0, stream);
  }
  if (st != hipSuccess) {
    // fallback: identical math as a multi-kernel sequence
    setup_k<<<512, 128, 0, stream>>>(p);
    for (int n = 0; n < 8; ++n) {
      for (int e = 1; e <= 4; ++e) {
        gemm1_k<<<512, 128, 0, stream>>>(p, e);
        gemm2_k<<<512, 128, 0, stream>>>(p);
        combine_k<<<512, 128, 0, stream>>>(p, n, e);
      }
    }
    tail_k<<<512, 128, 0, stream>>>(p);
  }
}